// Round 1
// baseline (318.642 us; speedup 1.0000x reference)
//
#include <hip/hip_runtime.h>
#include <hip/hip_bf16.h>

#define LOG2E 1.4426950408889634f

// ---------------- Kernel 1: fused q/kv projection (fp32 GEMM) ----------------
// out[o,p] = sum_c W[o][c] * x[b][c][p]; o in [0,512): o<128 -> q, else kv.
// q written in (z=b*8+head, nb, qidx, d) layout; kv in natural (b, ch, y, x).
__global__ __launch_bounds__(256) void haloattn_proj(
    const float* __restrict__ x, const float* __restrict__ q_w,
    const float* __restrict__ kv_w, float* __restrict__ q_ws,
    float* __restrict__ kv_ws)
{
  const int b  = blockIdx.z;
  const int o0 = blockIdx.y << 6;
  const int p0 = blockIdx.x << 6;   // p0 = y*64 -> one whole pixel row
  const int tid = threadIdx.x;
  const int to = tid >> 4;          // 0..15
  const int tp = tid & 15;          // 0..15

  __shared__ float As[16][68];      // [kk][oo]
  __shared__ float Bs[16][68];      // [kk][pp]

  float acc[4][4] = {};

  const float* xb = x + (size_t)b * (256 * 4096);
  const int oo = tid >> 2;          // 0..63
  const int kc = (tid & 3) << 2;    // 0,4,8,12
  const int o_l = o0 + oo;
  const float* wrow = (o_l < 128) ? (q_w + (size_t)o_l * 256)
                                  : (kv_w + (size_t)(o_l - 128) * 256);
  const int kkB = tid >> 4;         // 0..15
  const int ppB = (tid & 15) << 2;  // 0..60

  for (int c0 = 0; c0 < 256; c0 += 16) {
    float4 a4 = *(const float4*)(wrow + c0 + kc);
    float4 b4 = *(const float4*)(xb + (size_t)(c0 + kkB) * 4096 + p0 + ppB);
    As[kc + 0][oo] = a4.x;
    As[kc + 1][oo] = a4.y;
    As[kc + 2][oo] = a4.z;
    As[kc + 3][oo] = a4.w;
    *(float4*)&Bs[kkB][ppB] = b4;
    __syncthreads();
#pragma unroll
    for (int kk = 0; kk < 16; ++kk) {
      const float4 av = *(const float4*)&As[kk][to << 2];
      const float4 bv = *(const float4*)&Bs[kk][tp << 2];
      float a[4] = {av.x, av.y, av.z, av.w};
      float bb[4] = {bv.x, bv.y, bv.z, bv.w};
#pragma unroll
      for (int i = 0; i < 4; ++i)
#pragma unroll
        for (int j = 0; j < 4; ++j)
          acc[i][j] = fmaf(a[i], bb[j], acc[i][j]);
    }
    __syncthreads();
  }

  const int y = blockIdx.x;          // pixel row
  if (o0 < 128) {
    const int o = o0 + (to << 2);    // 4 consecutive o, same head (d0 in {0,4,8,12})
    const int head = o >> 4;
    const int d0 = o & 15;
    const int z = (b << 3) + head;
    const int bi = y >> 3, qh = y & 7;
#pragma unroll
    for (int j = 0; j < 4; ++j) {
      const int xq = (tp << 2) + j;
      const int bj = xq >> 3, qw = xq & 7;
      const int nb = (bi << 3) + bj;
      const int qi = (qh << 3) + qw;
      float4 v = make_float4(acc[0][j], acc[1][j], acc[2][j], acc[3][j]);
      *(float4*)(q_ws + ((((size_t)z << 6) + nb) << 10) + (qi << 4) + d0) = v;
    }
  } else {
    const int ch = o0 - 128 + (to << 2);
#pragma unroll
    for (int i = 0; i < 4; ++i) {
      float4 v = make_float4(acc[i][0], acc[i][1], acc[i][2], acc[i][3]);
      *(float4*)(kv_ws + ((size_t)b * 384 + ch + i) * 4096 + p0 + (tp << 2)) = v;
    }
  }
}

// ---------------- Kernel 2: halo attention (flash-style, fp32) ----------------
// block = (z, nb); 256 threads = 4 waves; lane=query, wave g owns rows i%4==g.
__global__ __launch_bounds__(256) void haloattn_attn(
    const float* __restrict__ q_ws, const float* __restrict__ kv_ws,
    const float* __restrict__ height_rel, const float* __restrict__ width_rel,
    float* __restrict__ out)
{
  __shared__ float smem[10976];     // K[196][20] + V[196][36]; reused for merge
  float* K_lds = smem;
  float* V_lds = smem + 196 * 20;

  const int tid = threadIdx.x;
  const int q   = tid & 63;
  const int g   = tid >> 6;
  const int nb  = blockIdx.x;
  const int z   = blockIdx.y;
  const int b = z >> 3, head = z & 7;
  const int bi = nb >> 3, bj = nb & 7;

  const float* kvb = kv_ws + ((size_t)b * 384 + head * 48) * 4096;
  // K: channels [48h, 48h+16)
  for (int e = tid; e < 196 * 16; e += 256) {
    const int d = e / 196;
    const int k = e - d * 196;
    const int i = k / 14;
    const int j = k - i * 14;
    const int yy = (bi << 3) + i - 3;
    const int xx = (bj << 3) + j - 3;
    float v = 0.f;
    if ((unsigned)yy < 64u && (unsigned)xx < 64u)
      v = kvb[(size_t)d * 4096 + (yy << 6) + xx];
    K_lds[k * 20 + d] = v;
  }
  // V: channels [48h+16, 48h+48)
  for (int e = tid; e < 196 * 32; e += 256) {
    const int d = e / 196;
    const int k = e - d * 196;
    const int i = k / 14;
    const int j = k - i * 14;
    const int yy = (bi << 3) + i - 3;
    const int xx = (bj << 3) + j - 3;
    float v = 0.f;
    if ((unsigned)yy < 64u && (unsigned)xx < 64u)
      v = kvb[(size_t)(16 + d) * 4096 + (yy << 6) + xx];
    V_lds[k * 36 + d] = v;
  }

  const int qh = q >> 3, qw = q & 7;
  float qv[16];
  {
    const float4* qp = (const float4*)(q_ws + ((((size_t)z << 6) + nb) << 10) + (q << 4));
    float4 t0 = qp[0], t1 = qp[1], t2 = qp[2], t3 = qp[3];
    qv[0]=t0.x; qv[1]=t0.y; qv[2]=t0.z; qv[3]=t0.w;
    qv[4]=t1.x; qv[5]=t1.y; qv[6]=t1.z; qv[7]=t1.w;
    qv[8]=t2.x; qv[9]=t2.y; qv[10]=t2.z; qv[11]=t2.w;
    qv[12]=t3.x; qv[13]=t3.y; qv[14]=t3.z; qv[15]=t3.w;
  }
  // width rel logits (compile-time indexed later by key col j)
  float rw[14];
#pragma unroll
  for (int j = 0; j < 14; ++j) {
    const float* wr = width_rel + (j - qw + 13) * 16;
    float s = 0.f;
#pragma unroll
    for (int d = 0; d < 16; ++d) s = fmaf(qv[d], wr[d], s);
    rw[j] = s * LOG2E;
  }
  // scale q once for K dots: SCALE*LOG2E
#pragma unroll
  for (int d = 0; d < 16; ++d) qv[d] *= 0.25f * LOG2E;

  __syncthreads();

  float m = -1e30f, l = 0.f;
  float acc[32] = {};

#pragma unroll
  for (int ii = 0; ii < 4; ++ii) {
    const int i = g + (ii << 2);       // wave-uniform row index
    if (i < 14) {
      // height rel for this row: qv is scaled by SCALE*LOG2E -> *4 gives LOG2E*(q.hr)
      const float* hr = height_rel + (i - qh + 13) * 16;
      float rhi = 0.f;
#pragma unroll
      for (int d = 0; d < 16; ++d) rhi = fmaf(qv[d], hr[d], rhi);
      rhi *= 4.f;

      float s[14];
#pragma unroll
      for (int j = 0; j < 14; ++j) {
        const float* kr = K_lds + (i * 14 + j) * 20;
        float dot = 0.f;
#pragma unroll
        for (int dd = 0; dd < 4; ++dd) {
          const float4 k4 = *(const float4*)(kr + (dd << 2));
          dot = fmaf(qv[dd * 4 + 0], k4.x, dot);
          dot = fmaf(qv[dd * 4 + 1], k4.y, dot);
          dot = fmaf(qv[dd * 4 + 2], k4.z, dot);
          dot = fmaf(qv[dd * 4 + 3], k4.w, dot);
        }
        s[j] = dot + rhi + rw[j];
      }
      float cm = s[0];
#pragma unroll
      for (int j = 1; j < 14; ++j) cm = fmaxf(cm, s[j]);
      const float nm = fmaxf(m, cm);
      const float r = exp2f(m - nm);
      l *= r;
#pragma unroll
      for (int d = 0; d < 32; ++d) acc[d] *= r;
      m = nm;
#pragma unroll
      for (int j = 0; j < 14; ++j) {
        const float p = exp2f(s[j] - m);
        l += p;
        const float* vr = V_lds + (i * 14 + j) * 36;
#pragma unroll
        for (int dd = 0; dd < 8; ++dd) {
          const float4 v4 = *(const float4*)(vr + (dd << 2));
          acc[dd * 4 + 0] = fmaf(p, v4.x, acc[dd * 4 + 0]);
          acc[dd * 4 + 1] = fmaf(p, v4.y, acc[dd * 4 + 1]);
          acc[dd * 4 + 2] = fmaf(p, v4.z, acc[dd * 4 + 2]);
          acc[dd * 4 + 3] = fmaf(p, v4.w, acc[dd * 4 + 3]);
        }
      }
    }
  }

  // ---- merge the 4 key-groups (reuse LDS) ----
  __syncthreads();
  {
    float* slot = smem + tid * 34;
    slot[0] = m; slot[1] = l;
#pragma unroll
    for (int d = 0; d < 32; ++d) slot[2 + d] = acc[d];
  }
  __syncthreads();

  float ms[4], ls[4];
#pragma unroll
  for (int gg = 0; gg < 4; ++gg) {
    const float* s2 = smem + (((gg << 6) + q) * 34);
    ms[gg] = s2[0]; ls[gg] = s2[1];
  }
  const float M = fmaxf(fmaxf(ms[0], ms[1]), fmaxf(ms[2], ms[3]));
  const float w0 = exp2f(ms[0] - M);
  const float w1 = exp2f(ms[1] - M);
  const float w2 = exp2f(ms[2] - M);
  const float w3 = exp2f(ms[3] - M);
  const float L = ls[0] * w0 + ls[1] * w1 + ls[2] * w2 + ls[3] * w3;
  const float invL = 1.f / L;

  float o8[8];
#pragma unroll
  for (int d = 0; d < 8; ++d) {
    const int c = 2 + (g << 3) + d;
    o8[d] = smem[(q) * 34 + c] * w0
          + smem[(64 + q) * 34 + c] * w1
          + smem[(128 + q) * 34 + c] * w2
          + smem[(192 + q) * 34 + c] * w3;
  }

  const int yq = (bi << 3) + qh;
  const int xq = (bj << 3) + qw;
  float* op = out + (((size_t)b * 256 + head * 32 + (g << 3)) * 64 + yq) * 64 + xq;
#pragma unroll
  for (int d = 0; d < 8; ++d)
    op[(size_t)d * 4096] = o8[d] * invL;
}

extern "C" void kernel_launch(void* const* d_in, const int* in_sizes, int n_in,
                              void* d_out, int out_size, void* d_ws, size_t ws_size,
                              hipStream_t stream) {
  const float* x          = (const float*)d_in[0];
  const float* q_w        = (const float*)d_in[1];
  const float* kv_w       = (const float*)d_in[2];
  const float* height_rel = (const float*)d_in[3];
  const float* width_rel  = (const float*)d_in[4];
  float* out = (float*)d_out;

  float* q_ws  = (float*)d_ws;                       // 64*64*64*16 = 4,194,304 f
  float* kv_ws = q_ws + (size_t)4194304;             // 8*384*4096 = 12,582,912 f

  dim3 gp(64, 8, 8);   // (p-tile=row, o-tile, batch)
  haloattn_proj<<<gp, 256, 0, stream>>>(x, q_w, kv_w, q_ws, kv_ws);

  dim3 ga(64, 64);     // (nb, z)
  haloattn_attn<<<ga, 256, 0, stream>>>(q_ws, kv_ws, height_rel, width_rel, out);
}

// Round 2
// 216.929 us; speedup vs baseline: 1.4689x; 1.4689x over previous
//
#include <hip/hip_runtime.h>
#include <hip/hip_bf16.h>

#define LOG2E 1.4426950408889634f

typedef __attribute__((ext_vector_type(8))) short bf16x8;
typedef __attribute__((ext_vector_type(4))) float f32x4;

__device__ __forceinline__ short f2bf(float a) {
  __hip_bfloat16 h = __float2bfloat16(a);
  return *reinterpret_cast<short*>(&h);
}
__device__ __forceinline__ unsigned pkbf(float a, float b) {
  return (unsigned)(unsigned short)f2bf(a) | ((unsigned)(unsigned short)f2bf(b) << 16);
}

union FragU { unsigned d[4]; bf16x8 v; };

// ---------------- Kernel 1: fused q/kv projection (fp32 GEMM) ----------------
// q written fp32 (z, nb, qidx, d); kv written BF16 in (b, y, x, 384) layout.
__global__ __launch_bounds__(256) void haloattn_proj(
    const float* __restrict__ x, const float* __restrict__ q_w,
    const float* __restrict__ kv_w, float* __restrict__ q_ws,
    unsigned short* __restrict__ kv_bf)
{
  const int b  = blockIdx.z;
  const int o0 = blockIdx.y << 6;
  const int p0 = blockIdx.x << 6;   // p0 = y*64 -> one whole pixel row
  const int tid = threadIdx.x;
  const int to = tid >> 4;          // 0..15
  const int tp = tid & 15;          // 0..15

  __shared__ float As[16][68];      // [kk][oo]
  __shared__ float Bs[16][68];      // [kk][pp]

  float acc[4][4] = {};

  const float* xb = x + (size_t)b * (256 * 4096);
  const int oo = tid >> 2;          // 0..63
  const int kc = (tid & 3) << 2;    // 0,4,8,12
  const int o_l = o0 + oo;
  const float* wrow = (o_l < 128) ? (q_w + (size_t)o_l * 256)
                                  : (kv_w + (size_t)(o_l - 128) * 256);
  const int kkB = tid >> 4;         // 0..15
  const int ppB = (tid & 15) << 2;  // 0..60

  for (int c0 = 0; c0 < 256; c0 += 16) {
    float4 a4 = *(const float4*)(wrow + c0 + kc);
    float4 b4 = *(const float4*)(xb + (size_t)(c0 + kkB) * 4096 + p0 + ppB);
    As[kc + 0][oo] = a4.x;
    As[kc + 1][oo] = a4.y;
    As[kc + 2][oo] = a4.z;
    As[kc + 3][oo] = a4.w;
    *(float4*)&Bs[kkB][ppB] = b4;
    __syncthreads();
#pragma unroll
    for (int kk = 0; kk < 16; ++kk) {
      const float4 av = *(const float4*)&As[kk][to << 2];
      const float4 bv = *(const float4*)&Bs[kk][tp << 2];
      float a[4] = {av.x, av.y, av.z, av.w};
      float bb[4] = {bv.x, bv.y, bv.z, bv.w};
#pragma unroll
      for (int i = 0; i < 4; ++i)
#pragma unroll
        for (int j = 0; j < 4; ++j)
          acc[i][j] = fmaf(a[i], bb[j], acc[i][j]);
    }
    __syncthreads();
  }

  const int y = blockIdx.x;          // pixel row
  if (o0 < 128) {
    const int o = o0 + (to << 2);    // 4 consecutive o, same head
    const int head = o >> 4;
    const int d0 = o & 15;
    const int z = (b << 3) + head;
    const int bi = y >> 3, qh = y & 7;
#pragma unroll
    for (int j = 0; j < 4; ++j) {
      const int xq = (tp << 2) + j;
      const int bj = xq >> 3, qw = xq & 7;
      const int nb = (bi << 3) + bj;
      const int qi = (qh << 3) + qw;
      float4 v = make_float4(acc[0][j], acc[1][j], acc[2][j], acc[3][j]);
      *(float4*)(q_ws + ((((size_t)z << 6) + nb) << 10) + (qi << 4) + d0) = v;
    }
  } else {
    const int ch0 = o0 - 128 + (to << 2);   // multiple of 4, in [0,384)
#pragma unroll
    for (int j = 0; j < 4; ++j) {
      const int pos = p0 + (tp << 2) + j;   // y*64 + x
      uint2 v;
      v.x = pkbf(acc[0][j], acc[1][j]);
      v.y = pkbf(acc[2][j], acc[3][j]);
      *(uint2*)(kv_bf + ((size_t)b * 4096 + pos) * 384 + ch0) = v;
    }
  }
}

// ---------------- Kernel 2: halo attention, MFMA (1 wave / tile) ----------------
// S^T = K·Q^T (16x16x32 bf16, c padded to 32); online softmax in C-layout;
// out^T = V^T·P^T with P^T repacked in-register via ds_bpermute.
__global__ __launch_bounds__(64) void haloattn_attn_mfma(
    const float* __restrict__ q_ws, const unsigned short* __restrict__ kv_bf,
    const float* __restrict__ height_rel, const float* __restrict__ width_rel,
    float* __restrict__ out)
{
  __shared__ float Hp[64][18];
  __shared__ float Wp[64][18];
  __shared__ unsigned short K_lds[32][40];  // [key][c], c>=16 stays zero
  __shared__ unsigned short V_lds[32][40];  // [d][key]  (V^T)

  const int l = threadIdx.x;
  const int g = l >> 4, c = l & 15;
  const int nb = blockIdx.x, z = blockIdx.y;
  const int b = z >> 3, head = z & 7;
  const int bi = nb >> 3, bj = nb & 7;

  const float* qtile = q_ws + ((((size_t)z << 6) + nb) << 10);

  // ---- prologue: H'/W' gather tables (one q-row per lane) ----
  {
    const int q = l, qh = l >> 3, qw = l & 7;
    float qr[16];
    const float4* qp = (const float4*)(qtile + (q << 4));
    float4 t0 = qp[0], t1 = qp[1], t2 = qp[2], t3 = qp[3];
    qr[0]=t0.x; qr[1]=t0.y; qr[2]=t0.z; qr[3]=t0.w;
    qr[4]=t1.x; qr[5]=t1.y; qr[6]=t1.z; qr[7]=t1.w;
    qr[8]=t2.x; qr[9]=t2.y; qr[10]=t2.z; qr[11]=t2.w;
    qr[12]=t3.x; qr[13]=t3.y; qr[14]=t3.z; qr[15]=t3.w;
#pragma unroll 2
    for (int i = 0; i < 14; ++i) {
      const float* hr = height_rel + (i - qh + 13) * 16;
      const float* wr = width_rel + (i - qw + 13) * 16;
      float sh = 0.f, sw = 0.f;
#pragma unroll
      for (int d = 0; d < 16; ++d) { sh = fmaf(qr[d], hr[d], sh); sw = fmaf(qr[d], wr[d], sw); }
      Hp[q][i] = sh * LOG2E;
      Wp[q][i] = sw * LOG2E;
    }
  }
  // zero the c in [16,32) region of K_lds (never written by staging)
  {
    uint4 z4 = {};
    *(uint4*)((char*)&K_lds[l >> 1][0] + 32 + ((l & 1) << 4)) = z4;
  }

  // ---- Q fragments (B-operand): lane holds Q[q=16nt+c][k=8g+i], g>=2 zero ----
  bf16x8 qfrag[4];
  const float qsc = 0.25f * LOG2E;
#pragma unroll
  for (int nt = 0; nt < 4; ++nt) {
    bf16x8 qq = {};
    if (g < 2) {
      const float* qp = qtile + (((nt << 4) + c) << 4) + (g << 3);
      float4 a = *(const float4*)qp;
      float4 b2 = *(const float4*)(qp + 4);
      qq[0] = f2bf(a.x * qsc);  qq[1] = f2bf(a.y * qsc);
      qq[2] = f2bf(a.z * qsc);  qq[3] = f2bf(a.w * qsc);
      qq[4] = f2bf(b2.x * qsc); qq[5] = f2bf(b2.y * qsc);
      qq[6] = f2bf(b2.z * qsc); qq[7] = f2bf(b2.w * qsc);
    }
    qfrag[nt] = qq;
  }
  __syncthreads();

  f32x4 acc[2][4] = {};   // [dt][nt], out^T tiles
  float mrow[4] = {-1e30f, -1e30f, -1e30f, -1e30f};
  float lrow[4] = {0.f, 0.f, 0.f, 0.f};
  const f32x4 zero4 = {0.f, 0.f, 0.f, 0.f};

  for (int chk = 0; chk < 7; ++chk) {
    // ---- stage K chunk: lane -> key l>>1, c-half (l&1)*8 ----
    {
      const int key = chk * 32 + (l >> 1);
      const int kcl = key < 196 ? key : 0;
      const int ki = kcl / 14, kj = kcl - (kcl / 14) * 14;
      const int yy = bi * 8 + ki - 3, xx = bj * 8 + kj - 3;
      uint4 kval = {};
      if (key < 196 && (unsigned)yy < 64u && (unsigned)xx < 64u)
        kval = *(const uint4*)(kv_bf + ((size_t)((b << 12) + (yy << 6) + xx)) * 384
                               + head * 48 + ((l & 1) << 3));
      *(uint4*)((char*)&K_lds[l >> 1][0] + ((l & 1) << 4)) = kval;
    }
    // ---- stage V chunk (transposed): lane -> key l&31, d-half (l>>5)*16 ----
    {
      const int keyl = l & 31;
      const int dh = (l >> 5) << 4;
      const int key = chk * 32 + keyl;
      const int kcl = key < 196 ? key : 0;
      const int ki = kcl / 14, kj = kcl - (kcl / 14) * 14;
      const int yy = bi * 8 + ki - 3, xx = bj * 8 + kj - 3;
      uint4 v0 = {}, v1 = {};
      if (key < 196 && (unsigned)yy < 64u && (unsigned)xx < 64u) {
        const unsigned short* p = kv_bf + ((size_t)((b << 12) + (yy << 6) + xx)) * 384
                                  + head * 48 + 16 + dh;
        v0 = *(const uint4*)p;
        v1 = *(const uint4*)(p + 8);
      }
      const unsigned short* sv0 = (const unsigned short*)&v0;
      const unsigned short* sv1 = (const unsigned short*)&v1;
#pragma unroll
      for (int t = 0; t < 8; ++t) V_lds[dh + t][keyl] = sv0[t];
#pragma unroll
      for (int t = 0; t < 8; ++t) V_lds[dh + 8 + t][keyl] = sv1[t];
    }
    __syncthreads();

    // ---- fragments for this chunk ----
    bf16x8 kf0 = *(const bf16x8*)((char*)&K_lds[c][0] + (g << 4));
    bf16x8 kf1 = *(const bf16x8*)((char*)&K_lds[16 + c][0] + (g << 4));
    bf16x8 vf0 = *(const bf16x8*)((char*)&V_lds[c][0] + (g << 4));
    bf16x8 vf1 = *(const bf16x8*)((char*)&V_lds[16 + c][0] + (g << 4));

#pragma unroll
    for (int nt = 0; nt < 4; ++nt) {
      f32x4 st0 = __builtin_amdgcn_mfma_f32_16x16x32_bf16(kf0, qfrag[nt], zero4, 0, 0, 0);
      f32x4 st1 = __builtin_amdgcn_mfma_f32_16x16x32_bf16(kf1, qfrag[nt], zero4, 0, 0, 0);
      const int q = (nt << 4) + c;
      float s[8];
#pragma unroll
      for (int mt = 0; mt < 2; ++mt)
#pragma unroll
        for (int r = 0; r < 4; ++r) {
          const int key = chk * 32 + (mt << 4) + (g << 2) + r;
          const int kcl = key < 196 ? key : 0;
          const int ki = kcl / 14;
          const int kj = kcl - ki * 14;
          float v = (mt ? st1[r] : st0[r]) + Hp[q][ki] + Wp[q][kj];
          s[mt * 4 + r] = (key < 196) ? v : -1e30f;
        }
      float cm = s[0];
#pragma unroll
      for (int t = 1; t < 8; ++t) cm = fmaxf(cm, s[t]);
      cm = fmaxf(cm, __shfl_xor(cm, 16));
      cm = fmaxf(cm, __shfl_xor(cm, 32));
      const float mo = mrow[nt];
      const float mn = fmaxf(mo, cm);
      const float rs = exp2f(mo - mn);
      mrow[nt] = mn;
      lrow[nt] *= rs;
      acc[0][nt] *= rs;
      acc[1][nt] *= rs;
      float p[8];
      float ls = 0.f;
#pragma unroll
      for (int t = 0; t < 8; ++t) { p[t] = exp2f(s[t] - mn); ls += p[t]; }
      lrow[nt] += ls;
      // ---- repack P (C-layout) -> B-fragment ----
      const unsigned dwA0 = pkbf(p[0], p[1]), dwA1 = pkbf(p[2], p[3]);
      const unsigned dwB0 = pkbf(p[4], p[5]), dwB1 = pkbf(p[6], p[7]);
      const int s1 = ((((g & 1) << 5) + c)) << 2;
      const int s2 = s1 + (16 << 2);
      const int a0 = __builtin_amdgcn_ds_bpermute(s1, (int)dwA0);
      const int a1 = __builtin_amdgcn_ds_bpermute(s1, (int)dwA1);
      const int a2 = __builtin_amdgcn_ds_bpermute(s2, (int)dwA0);
      const int a3 = __builtin_amdgcn_ds_bpermute(s2, (int)dwA1);
      const int b0 = __builtin_amdgcn_ds_bpermute(s1, (int)dwB0);
      const int b1 = __builtin_amdgcn_ds_bpermute(s1, (int)dwB1);
      const int b2 = __builtin_amdgcn_ds_bpermute(s2, (int)dwB0);
      const int b3 = __builtin_amdgcn_ds_bpermute(s2, (int)dwB1);
      FragU fu;
      const bool hi = (g >= 2);
      fu.d[0] = (unsigned)(hi ? b0 : a0);
      fu.d[1] = (unsigned)(hi ? b1 : a1);
      fu.d[2] = (unsigned)(hi ? b2 : a2);
      fu.d[3] = (unsigned)(hi ? b3 : a3);
      acc[0][nt] = __builtin_amdgcn_mfma_f32_16x16x32_bf16(vf0, fu.v, acc[0][nt], 0, 0, 0);
      acc[1][nt] = __builtin_amdgcn_mfma_f32_16x16x32_bf16(vf1, fu.v, acc[1][nt], 0, 0, 0);
    }
    __syncthreads();
  }

  // ---- epilogue ----
#pragma unroll
  for (int nt = 0; nt < 4; ++nt) {
    float ls = lrow[nt];
    ls += __shfl_xor(ls, 16);
    ls += __shfl_xor(ls, 32);
    const float il = 1.f / ls;
    const int q = (nt << 4) + c;
    const int yq = bi * 8 + (q >> 3), xq = bj * 8 + (q & 7);
#pragma unroll
    for (int dt = 0; dt < 2; ++dt) {
      const f32x4 o = acc[dt][nt];
#pragma unroll
      for (int r = 0; r < 4; ++r) {
        const int d = (dt << 4) + (g << 2) + r;
        out[(((size_t)b * 256 + head * 32 + d) * 64 + yq) * 64 + xq] = o[r] * il;
      }
    }
  }
}

extern "C" void kernel_launch(void* const* d_in, const int* in_sizes, int n_in,
                              void* d_out, int out_size, void* d_ws, size_t ws_size,
                              hipStream_t stream) {
  const float* x          = (const float*)d_in[0];
  const float* q_w        = (const float*)d_in[1];
  const float* kv_w       = (const float*)d_in[2];
  const float* height_rel = (const float*)d_in[3];
  const float* width_rel  = (const float*)d_in[4];
  float* out = (float*)d_out;

  float* q_ws = (float*)d_ws;                                   // 4,194,304 floats
  unsigned short* kv_bf = (unsigned short*)(q_ws + 4194304);    // 12,582,912 bf16

  dim3 gp(64, 8, 8);   // (p-tile=row, o-tile, batch)
  haloattn_proj<<<gp, 256, 0, stream>>>(x, q_w, kv_w, q_ws, kv_bf);

  dim3 ga(64, 64);     // (nb, z)
  haloattn_attn_mfma<<<ga, 64, 0, stream>>>(q_ws, kv_bf, height_rel, width_rel, out);
}

// Round 3
// 116.342 us; speedup vs baseline: 2.7389x; 1.8646x over previous
//
#include <hip/hip_runtime.h>
#include <hip/hip_bf16.h>

#define LOG2E 1.4426950408889634f

typedef __attribute__((ext_vector_type(8))) short bf16x8;
typedef __attribute__((ext_vector_type(4))) float f32x4;

__device__ __forceinline__ short f2bf(float a) {
  __hip_bfloat16 h = __float2bfloat16(a);
  return *reinterpret_cast<short*>(&h);
}
__device__ __forceinline__ float bf2f(unsigned short u) {
  unsigned v = ((unsigned)u) << 16;
  float f;
  __builtin_memcpy(&f, &v, 4);
  return f;
}
__device__ __forceinline__ unsigned pkbf(float a, float b) {
  return (unsigned)(unsigned short)f2bf(a) | ((unsigned)(unsigned short)f2bf(b) << 16);
}
union FragU { unsigned d[4]; bf16x8 v; };

// ---------------- Kernel 0: transpose-convert ----------------
// x fp32 [b][c=256][p=4096] -> xT bf16 [b][p][256]; also W fp32 -> w_bf bf16 [512][256].
__global__ __launch_bounds__(256) void haloattn_cvt(
    const float* __restrict__ x, const float* __restrict__ q_w,
    const float* __restrict__ kv_w, unsigned short* __restrict__ xT,
    unsigned short* __restrict__ w_bf)
{
  __shared__ float Ld[64][68];
  const int t = threadIdx.x;
  const int pt = blockIdx.x, kt = blockIdx.y, b = blockIdx.z;
  // W convert side-job: 2048 blocks x 64 elems
  {
    const int flat = ((b << 2) + kt) * 64 + pt;   // 0..2047
    const int idx = flat * 64 + (t & 63);
    if (t < 64) {
      const float wv = (idx < 32768) ? q_w[idx] : kv_w[idx - 32768];
      w_bf[idx] = (unsigned short)f2bf(wv);
    }
  }
  const float* xb = x + ((size_t)b * 256 + (kt << 6)) * 4096 + (pt << 6);
#pragma unroll
  for (int ps = 0; ps < 4; ++ps) {
    const int kloc = (ps << 4) + (t >> 4);
    const int ploc = (t & 15) << 2;
    float4 v = *(const float4*)(xb + (size_t)kloc * 4096 + ploc);
    *(float4*)&Ld[kloc][ploc] = v;
  }
  __syncthreads();
  const int pl = t >> 2;
  const int ks = (t & 3) << 4;
  float f[16];
#pragma unroll
  for (int i = 0; i < 16; ++i) f[i] = Ld[ks + i][pl];
  uint4 o0, o1;
  o0.x = pkbf(f[0], f[1]);   o0.y = pkbf(f[2], f[3]);
  o0.z = pkbf(f[4], f[5]);   o0.w = pkbf(f[6], f[7]);
  o1.x = pkbf(f[8], f[9]);   o1.y = pkbf(f[10], f[11]);
  o1.z = pkbf(f[12], f[13]); o1.w = pkbf(f[14], f[15]);
  unsigned short* op = xT + ((size_t)(b << 12) + (pt << 6) + pl) * 256 + (kt << 6) + ks;
  *(uint4*)op = o0;
  *(uint4*)(op + 8) = o1;
}

// ---------------- Kernel 1: fused q/kv projection (bf16 MFMA) ----------------
// C[o][p] = sum_c W[o][c] X[c][p]. BM=256 o x BN=128 p per block, 8 waves 64x64.
// q stored bf16 (z, nb, qi, d); kv stored bf16 (b, y, x, 384).
__global__ __launch_bounds__(512, 4) void haloattn_proj_mfma(
    const unsigned short* __restrict__ xT, const unsigned short* __restrict__ w_bf,
    unsigned short* __restrict__ q_bf, unsigned short* __restrict__ kv_bf)
{
  __shared__ unsigned short Wt[256][68];
  __shared__ unsigned short Xt[128][68];
  const int tid = threadIdx.x;
  const int w = tid >> 6, l = tid & 63;
  const int b = blockIdx.z, oBase = blockIdx.y << 8, pBase = blockIdx.x << 7;
  const int wm = w >> 1, wn = w & 1;       // wave tile: 64 o x 64 p
  const int g = l >> 4, c = l & 15;

  f32x4 acc[4][4] = {};                    // [mf][nf]

  const int srow = tid >> 3;               // 0..63
  const int se3  = (tid & 7) << 3;         // k elem offset 0..56

  for (int chk = 0; chk < 4; ++chk) {
    const int k0 = chk << 6;
    // stage W[256][64] (bf16, from cache-resident w_bf)
#pragma unroll
    for (int ps = 0; ps < 4; ++ps) {
      const int row = (ps << 6) + srow;
      uint4 wv = *(const uint4*)(w_bf + (size_t)(oBase + row) * 256 + k0 + se3);
      char* dst = (char*)&Wt[0][0] + row * 136 + (se3 << 1);
      *(uint2*)dst = make_uint2(wv.x, wv.y);
      *(uint2*)(dst + 8) = make_uint2(wv.z, wv.w);
    }
    // stage X^T[128][64]
#pragma unroll
    for (int ps = 0; ps < 2; ++ps) {
      const int p = (ps << 6) + srow;
      uint4 xv = *(const uint4*)(xT + ((size_t)(b << 12) + pBase + p) * 256 + k0 + se3);
      char* dst = (char*)&Xt[0][0] + p * 136 + (se3 << 1);
      *(uint2*)dst = make_uint2(xv.x, xv.y);
      *(uint2*)(dst + 8) = make_uint2(xv.z, xv.w);
    }
    __syncthreads();
#pragma unroll
    for (int kk = 0; kk < 2; ++kk) {
      FragU bfr[4];
#pragma unroll
      for (int nf = 0; nf < 4; ++nf) {
        const char* src = (const char*)&Xt[0][0]
            + ((wn << 6) + (nf << 4) + c) * 136 + (kk << 6) + (g << 4);
        uint2 lo = *(const uint2*)src, hi = *(const uint2*)(src + 8);
        bfr[nf].d[0] = lo.x; bfr[nf].d[1] = lo.y;
        bfr[nf].d[2] = hi.x; bfr[nf].d[3] = hi.y;
      }
#pragma unroll
      for (int mf = 0; mf < 4; ++mf) {
        const char* src = (const char*)&Wt[0][0]
            + ((wm << 6) + (mf << 4) + c) * 136 + (kk << 6) + (g << 4);
        uint2 lo = *(const uint2*)src, hi = *(const uint2*)(src + 8);
        FragU af;
        af.d[0] = lo.x; af.d[1] = lo.y; af.d[2] = hi.x; af.d[3] = hi.y;
#pragma unroll
        for (int nf = 0; nf < 4; ++nf)
          acc[mf][nf] = __builtin_amdgcn_mfma_f32_16x16x32_bf16(af.v, bfr[nf].v, acc[mf][nf], 0, 0, 0);
      }
    }
    __syncthreads();
  }
  // ---- store (bf16 quads along o/d) ----
#pragma unroll
  for (int mf = 0; mf < 4; ++mf) {
    const int o = oBase + (wm << 6) + (mf << 4) + (g << 2);
#pragma unroll
    for (int nf = 0; nf < 4; ++nf) {
      const int p = pBase + (wn << 6) + (nf << 4) + c;
      uint2 pk2 = make_uint2(pkbf(acc[mf][nf][0], acc[mf][nf][1]),
                             pkbf(acc[mf][nf][2], acc[mf][nf][3]));
      if (o < 128) {
        const int head = o >> 4;
        const int z = (b << 3) + head;
        const int y = p >> 6, xx = p & 63;
        const int nb = ((y >> 3) << 3) + (xx >> 3);
        const int qi = ((y & 7) << 3) + (xx & 7);
        *(uint2*)(q_bf + (((size_t)z * 64 + nb) * 64 + qi) * 16 + (o & 15)) = pk2;
      } else {
        *(uint2*)(kv_bf + ((size_t)(b << 12) + p) * 384 + (o - 128)) = pk2;
      }
    }
  }
}

// ---------------- Kernel 2: halo attention, MFMA (1 wave / tile) ----------------
__global__ __launch_bounds__(64) void haloattn_attn_mfma(
    const unsigned short* __restrict__ q_bf, const unsigned short* __restrict__ kv_bf,
    const float* __restrict__ height_rel, const float* __restrict__ width_rel,
    float* __restrict__ out)
{
  __shared__ float Hp[64][18];
  __shared__ float Wp[64][18];
  __shared__ unsigned short K_lds[32][40];  // [key][c], c>=16 stays zero
  __shared__ unsigned short V_lds[32][40];  // [d][key]  (V^T)

  const int l = threadIdx.x;
  const int g = l >> 4, c = l & 15;
  const int nb = blockIdx.x, z = blockIdx.y;
  const int b = z >> 3, head = z & 7;
  const int bi = nb >> 3, bj = nb & 7;

  const unsigned short* qtile = q_bf + (((size_t)z << 6) + nb) * 1024;

  // ---- prologue: H'/W' gather tables (one q-row per lane) ----
  {
    const int q = l, qh = l >> 3, qw = l & 7;
    const unsigned short* qp = qtile + (q << 4);
    uint4 a = *(const uint4*)qp;
    uint4 b2 = *(const uint4*)(qp + 8);
    unsigned ua[8] = {a.x, a.y, a.z, a.w, b2.x, b2.y, b2.z, b2.w};
    float qr[16];
#pragma unroll
    for (int j = 0; j < 8; ++j) {
      qr[2 * j]     = bf2f((unsigned short)(ua[j] & 0xffffu));
      qr[2 * j + 1] = bf2f((unsigned short)(ua[j] >> 16));
    }
#pragma unroll 2
    for (int i = 0; i < 14; ++i) {
      const float* hr = height_rel + (i - qh + 13) * 16;
      const float* wr = width_rel + (i - qw + 13) * 16;
      float sh = 0.f, sw = 0.f;
#pragma unroll
      for (int d = 0; d < 16; ++d) { sh = fmaf(qr[d], hr[d], sh); sw = fmaf(qr[d], wr[d], sw); }
      Hp[q][i] = sh * LOG2E;
      Wp[q][i] = sw * LOG2E;
    }
  }
  // zero the c in [16,32) region of K_lds
  {
    uint4 z4 = {};
    *(uint4*)((char*)&K_lds[l >> 1][0] + 32 + ((l & 1) << 4)) = z4;
  }

  // ---- Q fragments (B-operand), unscaled bf16 ----
  bf16x8 qfrag[4];
#pragma unroll
  for (int nt = 0; nt < 4; ++nt) {
    bf16x8 qq = {};
    if (g < 2)
      qq = *(const bf16x8*)(qtile + (((nt << 4) + c) << 4) + (g << 3));
    qfrag[nt] = qq;
  }
  __syncthreads();

  f32x4 acc[2][4] = {};
  float mrow[4] = {-1e30f, -1e30f, -1e30f, -1e30f};
  float lrow[4] = {0.f, 0.f, 0.f, 0.f};
  const f32x4 zero4 = {0.f, 0.f, 0.f, 0.f};
  const float qs = 0.25f * LOG2E;

  for (int chk = 0; chk < 7; ++chk) {
    // ---- stage K chunk ----
    {
      const int key = chk * 32 + (l >> 1);
      const int kcl = key < 196 ? key : 0;
      const int ki = kcl / 14, kj = kcl - (kcl / 14) * 14;
      const int yy = bi * 8 + ki - 3, xx = bj * 8 + kj - 3;
      uint4 kval = {};
      if (key < 196 && (unsigned)yy < 64u && (unsigned)xx < 64u)
        kval = *(const uint4*)(kv_bf + ((size_t)((b << 12) + (yy << 6) + xx)) * 384
                               + head * 48 + ((l & 1) << 3));
      *(uint4*)((char*)&K_lds[l >> 1][0] + ((l & 1) << 4)) = kval;
    }
    // ---- stage V chunk (transposed) ----
    {
      const int keyl = l & 31;
      const int dh = (l >> 5) << 4;
      const int key = chk * 32 + keyl;
      const int kcl = key < 196 ? key : 0;
      const int ki = kcl / 14, kj = kcl - (kcl / 14) * 14;
      const int yy = bi * 8 + ki - 3, xx = bj * 8 + kj - 3;
      uint4 v0 = {}, v1 = {};
      if (key < 196 && (unsigned)yy < 64u && (unsigned)xx < 64u) {
        const unsigned short* p = kv_bf + ((size_t)((b << 12) + (yy << 6) + xx)) * 384
                                  + head * 48 + 16 + dh;
        v0 = *(const uint4*)p;
        v1 = *(const uint4*)(p + 8);
      }
      const unsigned short* sv0 = (const unsigned short*)&v0;
      const unsigned short* sv1 = (const unsigned short*)&v1;
#pragma unroll
      for (int t = 0; t < 8; ++t) V_lds[dh + t][keyl] = sv0[t];
#pragma unroll
      for (int t = 0; t < 8; ++t) V_lds[dh + 8 + t][keyl] = sv1[t];
    }
    __syncthreads();

    bf16x8 kf0 = *(const bf16x8*)((char*)&K_lds[c][0] + (g << 4));
    bf16x8 kf1 = *(const bf16x8*)((char*)&K_lds[16 + c][0] + (g << 4));
    bf16x8 vf0 = *(const bf16x8*)((char*)&V_lds[c][0] + (g << 4));
    bf16x8 vf1 = *(const bf16x8*)((char*)&V_lds[16 + c][0] + (g << 4));

#pragma unroll
    for (int nt = 0; nt < 4; ++nt) {
      f32x4 st0 = __builtin_amdgcn_mfma_f32_16x16x32_bf16(kf0, qfrag[nt], zero4, 0, 0, 0);
      f32x4 st1 = __builtin_amdgcn_mfma_f32_16x16x32_bf16(kf1, qfrag[nt], zero4, 0, 0, 0);
      const int q = (nt << 4) + c;
      float s[8];
#pragma unroll
      for (int mt = 0; mt < 2; ++mt)
#pragma unroll
        for (int r = 0; r < 4; ++r) {
          const int key = chk * 32 + (mt << 4) + (g << 2) + r;
          const int kcl = key < 196 ? key : 0;
          const int ki = kcl / 14;
          const int kj = kcl - ki * 14;
          float v = fmaf(mt ? st1[r] : st0[r], qs, Hp[q][ki] + Wp[q][kj]);
          s[mt * 4 + r] = (key < 196) ? v : -1e30f;
        }
      float cm = s[0];
#pragma unroll
      for (int t = 1; t < 8; ++t) cm = fmaxf(cm, s[t]);
      cm = fmaxf(cm, __shfl_xor(cm, 16));
      cm = fmaxf(cm, __shfl_xor(cm, 32));
      const float mo = mrow[nt];
      const float mn = fmaxf(mo, cm);
      const float rs = exp2f(mo - mn);
      mrow[nt] = mn;
      lrow[nt] *= rs;
      acc[0][nt] *= rs;
      acc[1][nt] *= rs;
      float p[8];
      float ls = 0.f;
#pragma unroll
      for (int t = 0; t < 8; ++t) { p[t] = exp2f(s[t] - mn); ls += p[t]; }
      lrow[nt] += ls;
      const unsigned dwA0 = pkbf(p[0], p[1]), dwA1 = pkbf(p[2], p[3]);
      const unsigned dwB0 = pkbf(p[4], p[5]), dwB1 = pkbf(p[6], p[7]);
      const int s1 = ((((g & 1) << 5) + c)) << 2;
      const int s2 = s1 + (16 << 2);
      const int a0 = __builtin_amdgcn_ds_bpermute(s1, (int)dwA0);
      const int a1 = __builtin_amdgcn_ds_bpermute(s1, (int)dwA1);
      const int a2 = __builtin_amdgcn_ds_bpermute(s2, (int)dwA0);
      const int a3 = __builtin_amdgcn_ds_bpermute(s2, (int)dwA1);
      const int b0 = __builtin_amdgcn_ds_bpermute(s1, (int)dwB0);
      const int b1 = __builtin_amdgcn_ds_bpermute(s1, (int)dwB1);
      const int b2 = __builtin_amdgcn_ds_bpermute(s2, (int)dwB0);
      const int b3 = __builtin_amdgcn_ds_bpermute(s2, (int)dwB1);
      FragU fu;
      const bool hi = (g >= 2);
      fu.d[0] = (unsigned)(hi ? b0 : a0);
      fu.d[1] = (unsigned)(hi ? b1 : a1);
      fu.d[2] = (unsigned)(hi ? b2 : a2);
      fu.d[3] = (unsigned)(hi ? b3 : a3);
      acc[0][nt] = __builtin_amdgcn_mfma_f32_16x16x32_bf16(vf0, fu.v, acc[0][nt], 0, 0, 0);
      acc[1][nt] = __builtin_amdgcn_mfma_f32_16x16x32_bf16(vf1, fu.v, acc[1][nt], 0, 0, 0);
    }
    __syncthreads();
  }

  // ---- epilogue ----
#pragma unroll
  for (int nt = 0; nt < 4; ++nt) {
    float ls = lrow[nt];
    ls += __shfl_xor(ls, 16);
    ls += __shfl_xor(ls, 32);
    const float il = 1.f / ls;
    const int q = (nt << 4) + c;
    const int yq = bi * 8 + (q >> 3), xq = bj * 8 + (q & 7);
#pragma unroll
    for (int dt = 0; dt < 2; ++dt) {
      const f32x4 o = acc[dt][nt];
#pragma unroll
      for (int r = 0; r < 4; ++r) {
        const int d = (dt << 4) + (g << 2) + r;
        out[(((size_t)b * 256 + head * 32 + d) * 64 + yq) * 64 + xq] = o[r] * il;
      }
    }
  }
}

extern "C" void kernel_launch(void* const* d_in, const int* in_sizes, int n_in,
                              void* d_out, int out_size, void* d_ws, size_t ws_size,
                              hipStream_t stream) {
  const float* x          = (const float*)d_in[0];
  const float* q_w        = (const float*)d_in[1];
  const float* kv_w       = (const float*)d_in[2];
  const float* height_rel = (const float*)d_in[3];
  const float* width_rel  = (const float*)d_in[4];
  float* out = (float*)d_out;

  unsigned short* q_bf  = (unsigned short*)d_ws;          // 4,194,304
  unsigned short* kv_bf = q_bf + (size_t)4194304;         // 12,582,912
  unsigned short* xT    = kv_bf + (size_t)12582912;       // 8,388,608
  unsigned short* w_bf  = xT + (size_t)8388608;           // 131,072

  haloattn_cvt<<<dim3(64, 4, 8), 256, 0, stream>>>(x, q_w, kv_w, xT, w_bf);
  haloattn_proj_mfma<<<dim3(32, 2, 8), 512, 0, stream>>>(xT, w_bf, q_bf, kv_bf);
  haloattn_attn_mfma<<<dim3(64, 64), 64, 0, stream>>>(q_bf, kv_bf, height_rel, width_rel, out);
}